// Round 2
// baseline (439.594 us; speedup 1.0000x reference)
//
#include <hip/hip_runtime.h>

// CrossNet: B=500000 rows, D=128, L=4.
//   x0 = inputs; xl = x0
//   for i in 0..L-1: s = dot(xl, w_i); xl = x0 * s + b_i + xl
//
// Affine refactor: xl stays in the family xl_i = alpha_i * x0 + beta_i,
// beta_i = sum_{j<i} b_j (row-independent, precomputed per thread),
//   alpha_{i+1} = alpha_i * (d_i + 1) + c_i,
//   d_i = dot(x0, w_i)    (4 INDEPENDENT butterflies -> pipelined),
//   c_i = dot(beta_i, w_i) (precomputed scalar).
// Output: out = alpha_L * x0 + beta_L.
//
// Layout: 32 lanes/row, one float4/lane. 2 rows per group per iteration for
// memory-level parallelism. Nontemporal stores (output never re-read).

#define CN_D 128
#define CN_L 4

// clang-native vector type: __builtin_nontemporal_store rejects HIP's
// float4 class but accepts ext_vector_type.
typedef float fvec4 __attribute__((ext_vector_type(4)));

__global__ __launch_bounds__(256) void crossnet_kernel(
    const float* __restrict__ inputs,
    const float* __restrict__ kernels,
    const float* __restrict__ biases,
    float* __restrict__ out,
    int nrows)
{
    const int lane = threadIdx.x & 31;          // float4 index within row
    const int grp_in_blk = threadIdx.x >> 5;    // 0..7
    const int grps_per_blk = blockDim.x >> 5;   // 8

    // Preload per-lane weight/bias fragments for all 4 layers (L2 broadcast).
    float4 w4[CN_L], b4[CN_L];
#pragma unroll
    for (int i = 0; i < CN_L; ++i) {
        w4[i] = ((const float4*)(kernels + i * CN_D))[lane];
        b4[i] = ((const float4*)(biases + i * CN_D))[lane];
    }

    // Precompute beta_L fragment and c[i] = dot(beta_i, w_i).
    float c[CN_L];
    float4 beta = make_float4(0.f, 0.f, 0.f, 0.f);
#pragma unroll
    for (int i = 0; i < CN_L; ++i) {
        float p = beta.x * w4[i].x + beta.y * w4[i].y
                + beta.z * w4[i].z + beta.w * w4[i].w;
        p += __shfl_xor(p, 1);
        p += __shfl_xor(p, 2);
        p += __shfl_xor(p, 4);
        p += __shfl_xor(p, 8);
        p += __shfl_xor(p, 16);
        c[i] = p;
        beta.x += b4[i].x; beta.y += b4[i].y;
        beta.z += b4[i].z; beta.w += b4[i].w;
    }

    const long long gsz = (long long)gridDim.x * grps_per_blk;

    for (long long rowA = (long long)blockIdx.x * grps_per_blk + grp_in_blk;
         rowA < nrows;
         rowA += 2 * gsz)
    {
        const long long rowB = rowA + gsz;
        const bool hasB = (rowB < nrows);             // uniform per group
        const long long rB = hasB ? rowB : rowA;      // clamp: keep load valid

        // Issue both row loads up front (MLP).
        float4 xA = ((const float4*)(inputs + rowA * CN_D))[lane];
        float4 xB = ((const float4*)(inputs + rB  * CN_D))[lane];

        // Per-lane partials of d_i = dot(x0, w_i): 8 independent values.
        float dA0 = xA.x*w4[0].x + xA.y*w4[0].y + xA.z*w4[0].z + xA.w*w4[0].w;
        float dA1 = xA.x*w4[1].x + xA.y*w4[1].y + xA.z*w4[1].z + xA.w*w4[1].w;
        float dA2 = xA.x*w4[2].x + xA.y*w4[2].y + xA.z*w4[2].z + xA.w*w4[2].w;
        float dA3 = xA.x*w4[3].x + xA.y*w4[3].y + xA.z*w4[3].z + xA.w*w4[3].w;
        float dB0 = xB.x*w4[0].x + xB.y*w4[0].y + xB.z*w4[0].z + xB.w*w4[0].w;
        float dB1 = xB.x*w4[1].x + xB.y*w4[1].y + xB.z*w4[1].z + xB.w*w4[1].w;
        float dB2 = xB.x*w4[2].x + xB.y*w4[2].y + xB.z*w4[2].z + xB.w*w4[2].w;
        float dB3 = xB.x*w4[3].x + xB.y*w4[3].y + xB.z*w4[3].z + xB.w*w4[3].w;

        // 8 independent butterfly chains, interleaved per step.
        dA0 += __shfl_xor(dA0, 1);  dA1 += __shfl_xor(dA1, 1);
        dA2 += __shfl_xor(dA2, 1);  dA3 += __shfl_xor(dA3, 1);
        dB0 += __shfl_xor(dB0, 1);  dB1 += __shfl_xor(dB1, 1);
        dB2 += __shfl_xor(dB2, 1);  dB3 += __shfl_xor(dB3, 1);

        dA0 += __shfl_xor(dA0, 2);  dA1 += __shfl_xor(dA1, 2);
        dA2 += __shfl_xor(dA2, 2);  dA3 += __shfl_xor(dA3, 2);
        dB0 += __shfl_xor(dB0, 2);  dB1 += __shfl_xor(dB1, 2);
        dB2 += __shfl_xor(dB2, 2);  dB3 += __shfl_xor(dB3, 2);

        dA0 += __shfl_xor(dA0, 4);  dA1 += __shfl_xor(dA1, 4);
        dA2 += __shfl_xor(dA2, 4);  dA3 += __shfl_xor(dA3, 4);
        dB0 += __shfl_xor(dB0, 4);  dB1 += __shfl_xor(dB1, 4);
        dB2 += __shfl_xor(dB2, 4);  dB3 += __shfl_xor(dB3, 4);

        dA0 += __shfl_xor(dA0, 8);  dA1 += __shfl_xor(dA1, 8);
        dA2 += __shfl_xor(dA2, 8);  dA3 += __shfl_xor(dA3, 8);
        dB0 += __shfl_xor(dB0, 8);  dB1 += __shfl_xor(dB1, 8);
        dB2 += __shfl_xor(dB2, 8);  dB3 += __shfl_xor(dB3, 8);

        dA0 += __shfl_xor(dA0, 16); dA1 += __shfl_xor(dA1, 16);
        dA2 += __shfl_xor(dA2, 16); dA3 += __shfl_xor(dA3, 16);
        dB0 += __shfl_xor(dB0, 16); dB1 += __shfl_xor(dB1, 16);
        dB2 += __shfl_xor(dB2, 16); dB3 += __shfl_xor(dB3, 16);

        // alpha recurrence: alpha_{i+1} = alpha_i*(d_i+1) + c_i
        float aA = 1.f, aB = 1.f;
        aA = fmaf(aA, dA0 + 1.f, c[0]);  aB = fmaf(aB, dB0 + 1.f, c[0]);
        aA = fmaf(aA, dA1 + 1.f, c[1]);  aB = fmaf(aB, dB1 + 1.f, c[1]);
        aA = fmaf(aA, dA2 + 1.f, c[2]);  aB = fmaf(aB, dB2 + 1.f, c[2]);
        aA = fmaf(aA, dA3 + 1.f, c[3]);  aB = fmaf(aB, dB3 + 1.f, c[3]);

        // out = alpha_L * x0 + beta_L  (nontemporal: never re-read)
        fvec4 oA, oB;
        oA.x = fmaf(aA, xA.x, beta.x);  oA.y = fmaf(aA, xA.y, beta.y);
        oA.z = fmaf(aA, xA.z, beta.z);  oA.w = fmaf(aA, xA.w, beta.w);
        oB.x = fmaf(aB, xB.x, beta.x);  oB.y = fmaf(aB, xB.y, beta.y);
        oB.z = fmaf(aB, xB.z, beta.z);  oB.w = fmaf(aB, xB.w, beta.w);

        __builtin_nontemporal_store(oA, (fvec4*)(out + rowA * CN_D) + lane);
        if (hasB)
            __builtin_nontemporal_store(oB, (fvec4*)(out + rowB * CN_D) + lane);
    }
}

extern "C" void kernel_launch(void* const* d_in, const int* in_sizes, int n_in,
                              void* d_out, int out_size, void* d_ws, size_t ws_size,
                              hipStream_t stream) {
    const float* inputs  = (const float*)d_in[0];
    const float* kernels = (const float*)d_in[1];
    const float* biases  = (const float*)d_in[2];
    float* out = (float*)d_out;

    const int nrows = in_sizes[0] / CN_D;  // 500000

    const int block = 256;                 // 8 row-groups per block
    const int grid  = 4096;                // 32768 groups; 2 rows/group/iter

    crossnet_kernel<<<grid, block, 0, stream>>>(inputs, kernels, biases, out, nrows);
}

// Round 3
// 419.671 us; speedup vs baseline: 1.0475x; 1.0475x over previous
//
#include <hip/hip_runtime.h>

// CrossNet: B=500000 rows, D=128, L=4.
//   x0 = inputs; xl = x0
//   for i: s = dot(xl, w_i); xl = x0*s + b_i + xl
// Affine form: xl_i = alpha_i*x0 + beta_i, beta = cumsum(b) (row-independent),
//   alpha_{i+1} = alpha_i*(d_i+1) + c_i,  d_i = dot(x0,w_i), c_i = dot(beta_i,w_i).
// Out = alpha_L*x0 + beta_L.
//
// Round-3 structure: 16 lanes per row (2 float4 chunks per lane) so the dot
// reduction fits a single 16-lane DPP row: quad_perm xor1/xor2 + row_ror:4/8.
// => ZERO LDS ops / zero lgkmcnt stalls in the main loop (round-2 had 40 ds
// ops + 5 serialized lgkm waits per iter; counters showed all pipes idle).
// Software prefetch: next row's loads issue BEFORE the current reduce, so the
// per-wave cadence is max(load_latency, compute) instead of their sum.
// Plain stores (NT stores correlated with the round-2 regression).

#define CN_D 128
#define CN_L 4

// 16-lane all-reduce, pure VALU (DPP). Every lane of each 16-lane row ends
// with the full 16-lane sum. quad_perm [1,0,3,2]=0xB1 (xor1),
// [2,3,0,1]=0x4E (xor2), row_ror:4=0x124, row_ror:8=0x128.
template <int CTRL>
__device__ __forceinline__ float dpp_radd(float x) {
    int t = __builtin_amdgcn_update_dpp(0, __float_as_int(x), CTRL, 0xF, 0xF, true);
    return x + __int_as_float(t);
}
__device__ __forceinline__ float row16_allreduce(float x) {
    x = dpp_radd<0xB1>(x);   // + lane^1
    x = dpp_radd<0x4E>(x);   // + lane^2  -> quad sums
    x = dpp_radd<0x124>(x);  // + rot4    -> 2-quad sums
    x = dpp_radd<0x128>(x);  // + rot8    -> full 16-lane sum, all lanes
    return x;
}

__global__ __launch_bounds__(256) void crossnet_kernel(
    const float* __restrict__ inputs,
    const float* __restrict__ kernels,
    const float* __restrict__ biases,
    float* __restrict__ out,
    int nrows)
{
    const int lane = threadIdx.x & 15;   // float4 chunk index (lo half)
    const int grp  = threadIdx.x >> 4;   // 0..15 row-groups per block
    const int gpb  = blockDim.x >> 4;    // 16 rows per block per iter

    // Per-lane weight fragments: chunks lane (lo) and lane+16 (hi), 4 layers.
    float4 wlo[CN_L], whi[CN_L];
#pragma unroll
    for (int i = 0; i < CN_L; ++i) {
        wlo[i] = ((const float4*)(kernels + i * CN_D))[lane];
        whi[i] = ((const float4*)(kernels + i * CN_D))[lane + 16];
    }

    // beta_L fragments and c[i] = dot(beta_i, w_i) (constants; reduction is
    // fully within the 16-lane row -> identical in every group).
    float c[CN_L];
    float4 blo = make_float4(0.f, 0.f, 0.f, 0.f);
    float4 bhi = make_float4(0.f, 0.f, 0.f, 0.f);
#pragma unroll
    for (int i = 0; i < CN_L; ++i) {
        float p = blo.x*wlo[i].x + blo.y*wlo[i].y + blo.z*wlo[i].z + blo.w*wlo[i].w
                + bhi.x*whi[i].x + bhi.y*whi[i].y + bhi.z*whi[i].z + bhi.w*whi[i].w;
        c[i] = row16_allreduce(p);
        float4 t;
        t = ((const float4*)(biases + i * CN_D))[lane];
        blo.x += t.x; blo.y += t.y; blo.z += t.z; blo.w += t.w;
        t = ((const float4*)(biases + i * CN_D))[lane + 16];
        bhi.x += t.x; bhi.y += t.y; bhi.z += t.z; bhi.w += t.w;
    }

    const int stride = gridDim.x * gpb;       // total row-groups
    int row = blockIdx.x * gpb + grp;
    if (row >= nrows) return;                 // no barriers in kernel: safe

    const float4* __restrict__ in4  = (const float4*)inputs;
    float4* __restrict__       out4 = (float4*)out;

    // Prime the pipeline.
    float4 xlo = in4[row * 32 + lane];
    float4 xhi = in4[row * 32 + lane + 16];

    while (true) {
        // ---- software prefetch: next row's loads in flight during reduce ----
        const int rnext = row + stride;
        const bool hasN = rnext < nrows;
        const int rn = hasN ? rnext : row;    // clamp keeps the load legal
        float4 nlo = in4[rn * 32 + lane];
        float4 nhi = in4[rn * 32 + lane + 16];

        // ---- 4 independent per-lane dot partials (8 elems each) ----
        float d0, d1, d2, d3;
        d0 = xlo.x * wlo[0].x;                 d1 = xlo.x * wlo[1].x;
        d2 = xlo.x * wlo[2].x;                 d3 = xlo.x * wlo[3].x;
        d0 = fmaf(xlo.y, wlo[0].y, d0);        d1 = fmaf(xlo.y, wlo[1].y, d1);
        d2 = fmaf(xlo.y, wlo[2].y, d2);        d3 = fmaf(xlo.y, wlo[3].y, d3);
        d0 = fmaf(xlo.z, wlo[0].z, d0);        d1 = fmaf(xlo.z, wlo[1].z, d1);
        d2 = fmaf(xlo.z, wlo[2].z, d2);        d3 = fmaf(xlo.z, wlo[3].z, d3);
        d0 = fmaf(xlo.w, wlo[0].w, d0);        d1 = fmaf(xlo.w, wlo[1].w, d1);
        d2 = fmaf(xlo.w, wlo[2].w, d2);        d3 = fmaf(xlo.w, wlo[3].w, d3);
        d0 = fmaf(xhi.x, whi[0].x, d0);        d1 = fmaf(xhi.x, whi[1].x, d1);
        d2 = fmaf(xhi.x, whi[2].x, d2);        d3 = fmaf(xhi.x, whi[3].x, d3);
        d0 = fmaf(xhi.y, whi[0].y, d0);        d1 = fmaf(xhi.y, whi[1].y, d1);
        d2 = fmaf(xhi.y, whi[2].y, d2);        d3 = fmaf(xhi.y, whi[3].y, d3);
        d0 = fmaf(xhi.z, whi[0].z, d0);        d1 = fmaf(xhi.z, whi[1].z, d1);
        d2 = fmaf(xhi.z, whi[2].z, d2);        d3 = fmaf(xhi.z, whi[3].z, d3);
        d0 = fmaf(xhi.w, whi[0].w, d0);        d1 = fmaf(xhi.w, whi[1].w, d1);
        d2 = fmaf(xhi.w, whi[2].w, d2);        d3 = fmaf(xhi.w, whi[3].w, d3);

        // ---- pure-VALU reductions (4 independent DPP chains) ----
        d0 = row16_allreduce(d0);
        d1 = row16_allreduce(d1);
        d2 = row16_allreduce(d2);
        d3 = row16_allreduce(d3);

        // ---- alpha recurrence ----
        float a = d0 + 1.f + c[0];
        a = fmaf(a, d1 + 1.f, c[1]);
        a = fmaf(a, d2 + 1.f, c[2]);
        a = fmaf(a, d3 + 1.f, c[3]);

        // ---- out = alpha*x0 + beta ----
        float4 olo, ohi;
        olo.x = fmaf(a, xlo.x, blo.x);  olo.y = fmaf(a, xlo.y, blo.y);
        olo.z = fmaf(a, xlo.z, blo.z);  olo.w = fmaf(a, xlo.w, blo.w);
        ohi.x = fmaf(a, xhi.x, bhi.x);  ohi.y = fmaf(a, xhi.y, bhi.y);
        ohi.z = fmaf(a, xhi.z, bhi.z);  ohi.w = fmaf(a, xhi.w, bhi.w);

        out4[row * 32 + lane]      = olo;
        out4[row * 32 + lane + 16] = ohi;

        if (!hasN) break;
        row = rnext;
        xlo = nlo;
        xhi = nhi;
    }
}

extern "C" void kernel_launch(void* const* d_in, const int* in_sizes, int n_in,
                              void* d_out, int out_size, void* d_ws, size_t ws_size,
                              hipStream_t stream) {
    const float* inputs  = (const float*)d_in[0];
    const float* kernels = (const float*)d_in[1];
    const float* biases  = (const float*)d_in[2];
    float* out = (float*)d_out;

    const int nrows = in_sizes[0] / CN_D;  // 500000

    const int block = 256;                 // 16 rows per block per iteration
    const int grid  = 4096;                // 65536 row-groups; ~7.6 iters each

    crossnet_kernel<<<grid, block, 0, stream>>>(inputs, kernels, biases, out, nrows);
}

// Round 4
// 409.978 us; speedup vs baseline: 1.0722x; 1.0236x over previous
//
#include <hip/hip_runtime.h>

// CrossNet: B=500000 rows, D=128, L=4.
//   x0 = inputs; xl = x0
//   for i: s = dot(xl, w_i); xl = x0*s + b_i + xl
// Affine form: xl_i = alpha_i*x0 + beta_i, beta = cumsum(b) (row-independent),
//   alpha_{i+1} = alpha_i*(d_i+1) + c_i,  d_i = dot(x0,w_i), c_i = dot(beta_i,w_i).
// Out = alpha_L*x0 + beta_L.
//
// Round-4 change (ONLY): nontemporal (no-allocate) on BOTH the streaming
// loads and stores. Rationale: the harness' reset fills ~1GB with allocating
// stores before each run, leaving L3 full of dirty lines; our allocating
// reads+writes then evict ~256MB of third-party dirty data during our
// dispatch (HBM traffic invisible to TCC FETCH/WRITE), explaining the
// measured ~3.7 TB/s vs the 6.3 TB/s the fills themselves reach.
// Streamed rows are touched exactly once -> caching them has zero value.
// Compute structure identical to round 3 (16-lane DPP reduce, prefetch).

#define CN_D 128
#define CN_L 4

typedef float fvec4 __attribute__((ext_vector_type(4)));

// 16-lane all-reduce, pure VALU (DPP). quad_perm [1,0,3,2]=0xB1 (xor1),
// [2,3,0,1]=0x4E (xor2), row_ror:4=0x124, row_ror:8=0x128.
template <int CTRL>
__device__ __forceinline__ float dpp_radd(float x) {
    int t = __builtin_amdgcn_update_dpp(0, __float_as_int(x), CTRL, 0xF, 0xF, true);
    return x + __int_as_float(t);
}
__device__ __forceinline__ float row16_allreduce(float x) {
    x = dpp_radd<0xB1>(x);   // + lane^1
    x = dpp_radd<0x4E>(x);   // + lane^2  -> quad sums
    x = dpp_radd<0x124>(x);  // + rot4    -> 2-quad sums
    x = dpp_radd<0x128>(x);  // + rot8    -> full 16-lane sum, all lanes
    return x;
}

__global__ __launch_bounds__(256) void crossnet_kernel(
    const float* __restrict__ inputs,
    const float* __restrict__ kernels,
    const float* __restrict__ biases,
    float* __restrict__ out,
    int nrows)
{
    const int lane = threadIdx.x & 15;   // float4 chunk index (lo half)
    const int grp  = threadIdx.x >> 4;   // 0..15 rows per block
    const int gpb  = blockDim.x >> 4;    // 16 rows per block per iter

    // Per-lane weight fragments (L2-resident broadcast; normal loads).
    float4 wlo[CN_L], whi[CN_L];
#pragma unroll
    for (int i = 0; i < CN_L; ++i) {
        wlo[i] = ((const float4*)(kernels + i * CN_D))[lane];
        whi[i] = ((const float4*)(kernels + i * CN_D))[lane + 16];
    }

    // beta_L fragments and c[i] = dot(beta_i, w_i).
    float c[CN_L];
    float4 blo = make_float4(0.f, 0.f, 0.f, 0.f);
    float4 bhi = make_float4(0.f, 0.f, 0.f, 0.f);
#pragma unroll
    for (int i = 0; i < CN_L; ++i) {
        float p = blo.x*wlo[i].x + blo.y*wlo[i].y + blo.z*wlo[i].z + blo.w*wlo[i].w
                + bhi.x*whi[i].x + bhi.y*whi[i].y + bhi.z*whi[i].z + bhi.w*whi[i].w;
        c[i] = row16_allreduce(p);
        float4 t;
        t = ((const float4*)(biases + i * CN_D))[lane];
        blo.x += t.x; blo.y += t.y; blo.z += t.z; blo.w += t.w;
        t = ((const float4*)(biases + i * CN_D))[lane + 16];
        bhi.x += t.x; bhi.y += t.y; bhi.z += t.z; bhi.w += t.w;
    }

    const int stride = gridDim.x * gpb;       // total rows per sweep
    int row = blockIdx.x * gpb + grp;
    if (row >= nrows) return;                 // no barriers: safe

    const fvec4* __restrict__ in4  = (const fvec4*)inputs;
    fvec4* __restrict__       out4 = (fvec4*)out;

    // Prime the pipeline (nontemporal: single-touch stream, don't allocate).
    fvec4 xlo = __builtin_nontemporal_load(in4 + row * 32 + lane);
    fvec4 xhi = __builtin_nontemporal_load(in4 + row * 32 + lane + 16);

    while (true) {
        // ---- prefetch next row while we reduce the current one ----
        const int rnext = row + stride;
        const bool hasN = rnext < nrows;
        const int rn = hasN ? rnext : row;    // clamp keeps the load legal
        fvec4 nlo = __builtin_nontemporal_load(in4 + rn * 32 + lane);
        fvec4 nhi = __builtin_nontemporal_load(in4 + rn * 32 + lane + 16);

        // ---- 4 independent per-lane dot partials (8 elems each) ----
        float d0, d1, d2, d3;
        d0 = xlo.x * wlo[0].x;                 d1 = xlo.x * wlo[1].x;
        d2 = xlo.x * wlo[2].x;                 d3 = xlo.x * wlo[3].x;
        d0 = fmaf(xlo.y, wlo[0].y, d0);        d1 = fmaf(xlo.y, wlo[1].y, d1);
        d2 = fmaf(xlo.y, wlo[2].y, d2);        d3 = fmaf(xlo.y, wlo[3].y, d3);
        d0 = fmaf(xlo.z, wlo[0].z, d0);        d1 = fmaf(xlo.z, wlo[1].z, d1);
        d2 = fmaf(xlo.z, wlo[2].z, d2);        d3 = fmaf(xlo.z, wlo[3].z, d3);
        d0 = fmaf(xlo.w, wlo[0].w, d0);        d1 = fmaf(xlo.w, wlo[1].w, d1);
        d2 = fmaf(xlo.w, wlo[2].w, d2);        d3 = fmaf(xlo.w, wlo[3].w, d3);
        d0 = fmaf(xhi.x, whi[0].x, d0);        d1 = fmaf(xhi.x, whi[1].x, d1);
        d2 = fmaf(xhi.x, whi[2].x, d2);        d3 = fmaf(xhi.x, whi[3].x, d3);
        d0 = fmaf(xhi.y, whi[0].y, d0);        d1 = fmaf(xhi.y, whi[1].y, d1);
        d2 = fmaf(xhi.y, whi[2].y, d2);        d3 = fmaf(xhi.y, whi[3].y, d3);
        d0 = fmaf(xhi.z, whi[0].z, d0);        d1 = fmaf(xhi.z, whi[1].z, d1);
        d2 = fmaf(xhi.z, whi[2].z, d2);        d3 = fmaf(xhi.z, whi[3].z, d3);
        d0 = fmaf(xhi.w, whi[0].w, d0);        d1 = fmaf(xhi.w, whi[1].w, d1);
        d2 = fmaf(xhi.w, whi[2].w, d2);        d3 = fmaf(xhi.w, whi[3].w, d3);

        // ---- pure-VALU reductions (4 independent DPP chains) ----
        d0 = row16_allreduce(d0);
        d1 = row16_allreduce(d1);
        d2 = row16_allreduce(d2);
        d3 = row16_allreduce(d3);

        // ---- alpha recurrence ----
        float a = d0 + 1.f + c[0];
        a = fmaf(a, d1 + 1.f, c[1]);
        a = fmaf(a, d2 + 1.f, c[2]);
        a = fmaf(a, d3 + 1.f, c[3]);

        // ---- out = alpha*x0 + beta (nontemporal store) ----
        fvec4 olo, ohi;
        olo.x = fmaf(a, xlo.x, blo.x);  olo.y = fmaf(a, xlo.y, blo.y);
        olo.z = fmaf(a, xlo.z, blo.z);  olo.w = fmaf(a, xlo.w, blo.w);
        ohi.x = fmaf(a, xhi.x, bhi.x);  ohi.y = fmaf(a, xhi.y, bhi.y);
        ohi.z = fmaf(a, xhi.z, bhi.z);  ohi.w = fmaf(a, xhi.w, bhi.w);

        __builtin_nontemporal_store(olo, out4 + row * 32 + lane);
        __builtin_nontemporal_store(ohi, out4 + row * 32 + lane + 16);

        if (!hasN) break;
        row = rnext;
        xlo = nlo;
        xhi = nhi;
    }
}

extern "C" void kernel_launch(void* const* d_in, const int* in_sizes, int n_in,
                              void* d_out, int out_size, void* d_ws, size_t ws_size,
                              hipStream_t stream) {
    const float* inputs  = (const float*)d_in[0];
    const float* kernels = (const float*)d_in[1];
    const float* biases  = (const float*)d_in[2];
    float* out = (float*)d_out;

    const int nrows = in_sizes[0] / CN_D;  // 500000

    const int block = 256;                 // 16 rows per block per iteration
    const int grid  = 4096;                // 65536 row-slots; ~7.6 iters each

    crossnet_kernel<<<grid, block, 0, stream>>>(inputs, kernels, biases, out, nrows);
}